// Round 19
// baseline (21.906 us; speedup 1.0000x reference)
//
#include <hip/hip_runtime.h>

// Problem constants (from reference setup_inputs)
#define B_  4
#define H_  64
#define W_  64
#define C_  16
#define F_  32

#define NWE (8 * 9 * F_)   // 2304 weight entries; each = {wt,wk} h2 pair = 8 B

typedef _Float16 h2 __attribute__((ext_vector_type(2)));

__device__ __forceinline__ h2 pack2(float a, float b) {
    h2 r; r.x = (_Float16)a; r.y = (_Float16)b; return r;
}
__device__ __forceinline__ float h2f(h2 v) { return __builtin_bit_cast(float, v); }

// acc += m.x + m.y (f32 accumulate of a packed f16 pair)
__device__ __forceinline__ float acc_dot2(h2 m, float c) {
#if __has_builtin(__builtin_amdgcn_fdot2)
    h2 one; one.x = (_Float16)1.0f; one.y = (_Float16)1.0f;
    return __builtin_amdgcn_fdot2(m, one, c, false);
#else
    return c + (float)m.x + (float)m.y;
#endif
}

// Prepacked weights in global: [ccp(8)][q(9)][f(32)] x {wt, wk} h2 pairs (18 KB)
__device__ h2 g_wpk[NWE * 2];

// ---- prep: rotate nothing (base orientation), just f32->h2 pack once ----
__global__ void mtp_prep(const float* __restrict__ kern,
                         const float* __restrict__ tker) {
    int e = blockIdx.x * 256 + threadIdx.x;      // 0..2303
    if (e >= NWE) return;
    int f   = e & 31;
    int t   = e >> 5;
    int q   = t % 9;
    int ccp = t / 9;
    int s0 = (q * C_ + ccp * 2) * F_ + f;        // channel ccp*2
    int s1 = s0 + F_;                            // channel ccp*2+1
    h2 wt = pack2(tker[s0], tker[s1]);           // times (slope)
    h2 wk = pack2(kern[s0], kern[s1]);           // plus (offset)
    *reinterpret_cast<float2*>(&g_wpk[e * 2]) = make_float2(h2f(wt), h2f(wk));
}

// Round-19: r13's proven inner loop, with staging cost attacked directly:
//  - weights prepacked to h2 by prep kernel -> main stage = pure b64 copy
//    (9 loads + 9 LDS writes/thread, zero cvt VALU; 18KB L2-hot, shared)
//  - quarter-row blocks (grid 1024 = exactly 4 blocks/CU in ONE round):
//    staging paid once in parallel chip-wide, not twice serially (r13),
//    and per-block x-stage is tiny (216 float4).
// r16/r18 failed because higher residency came WITH duplicated full staging;
// this decouples them. No launch_bounds floor (r4/r8/r11); cc-loop unroll 1.
__global__ __launch_bounds__(256) void mtp_main(const float* __restrict__ x,
                                                float* __restrict__ out) {
    __shared__ h2 wlds[NWE * 2];        // 18432 B, same layout as r13
    __shared__ h2 xlds[3][18][8];       // [row][padded col][ch pair] 1728 B

    const int tid  = threadIdx.x;
    const int bidx = blockIdx.x;        // (b*64 + i)*4 + q4
    const int q4   = bidx & 3;
    const int i    = (bidx >> 2) & 63;
    const int b    = bidx >> 8;
    const int jseg = q4 * 16;           // segment base column

    // ---- stage weights: pure coalesced b64 copy of prepacked h2 pairs ----
    {
        const float2* src = reinterpret_cast<const float2*>(g_wpk);
        float2* dst = reinterpret_cast<float2*>(wlds);
        #pragma unroll
        for (int e0 = 0; e0 < 9; ++e0)               // 2304 = 9*256
            dst[e0 * 256 + tid] = src[e0 * 256 + tid];
    }
    // ---- stage x halo (zero-padded): rows i-1..i+1, cols jseg-1..jseg+16 ----
    if (tid < 216) {                                  // 3*18*4 float4 chunks
        int cc4 = tid & 3;
        int t   = tid >> 2;
        int cl  = t % 18;                             // local padded col
        int di  = t / 18;
        int ro  = i + di - 1;
        int co  = jseg + cl - 1;
        float4 v = make_float4(0.f, 0.f, 0.f, 0.f);
        if (ro >= 0 && ro < H_ && co >= 0 && co < W_)
            v = *reinterpret_cast<const float4*>(
                    x + ((b * H_ + ro) * W_ + co) * C_ + cc4 * 4);
        xlds[di][cl][cc4 * 2 + 0] = pack2(v.x, v.y);
        xlds[di][cl][cc4 * 2 + 1] = pack2(v.z, v.w);
    }
    __syncthreads();

    const int lane = tid & 63;
    const int f    = lane & 31;
    const int ps   = lane >> 5;
    const int w    = tid >> 6;          // wave 0..3; strip = px w*4 .. w*4+3
    const int cb   = w * 4 + ps;        // padded-col base for lc=0

    float acc[2][4];                    // [it][r]
    #pragma unroll
    for (int it = 0; it < 2; ++it)
        #pragma unroll
        for (int r = 0; r < 4; ++r) acc[it][r] = 0.f;

    #pragma unroll 1
    for (int cc = 0; cc < 8; ++cc) {
        // weights: 9 x 8B merged ds_read (identical to r13)
        h2 wt[9], wk[9];
        #pragma unroll
        for (int q = 0; q < 9; ++q) {
            int bi = ((cc * 9 + q) * F_ + f) * 2;
            wt[q] = wlds[bi];
            wk[q] = wlds[bi + 1];
        }
        // x halo: 3 rows x 5 cols, 4B each (2 distinct addrs/wave -> broadcast)
        h2 xh[3][5];
        #pragma unroll
        for (int dr = 0; dr < 3; ++dr)
            #pragma unroll
            for (int lc = 0; lc < 5; ++lc)
                xh[dr][lc] = xlds[dr][cb + lc][cc];

        #pragma unroll
        for (int it = 0; it < 2; ++it) {
            #pragma unroll
            for (int r = 0; r < 4; ++r) {
                h2 z[9];
                #pragma unroll
                for (int q = 0; q < 9; ++q) {
                    const int a = q / 3, bq = q % 3;
                    int di, dj;
                    switch (r) {   // x position = rot_r^{-1}(weight position q)
                        case 0:  di = a;      dj = bq;     break;
                        case 1:  di = 2 - bq; dj = a;      break;
                        case 2:  di = 2 - a;  dj = 2 - bq; break;
                        default: di = bq;     dj = 2 - a;  break;
                    }
                    z[q] = xh[di][it * 2 + dj] * wt[q] + wk[q];   // v_pk_fma_f16
                }
                h2 m1 = __builtin_elementwise_max(__builtin_elementwise_max(z[0], z[1]), z[2]);
                h2 m2 = __builtin_elementwise_max(__builtin_elementwise_max(z[3], z[4]), z[5]);
                h2 m3 = __builtin_elementwise_max(__builtin_elementwise_max(z[6], z[7]), z[8]);
                h2 mm = __builtin_elementwise_max(__builtin_elementwise_max(m1, m2), m3);
                acc[it][r] = acc_dot2(mm, acc[it][r]);   // f32 accumulate
            }
        }
    }

    // ---- store: out[b, r, i, jg + it*2, f]; per (r,it) wave stores 256B
    const int jg = jseg + w * 4 + ps;
    #pragma unroll
    for (int r = 0; r < 4; ++r) {
        float* op = out + ((((b * 4 + r) * H_ + i) * W_ + jg) * F_ + f);
        #pragma unroll
        for (int it = 0; it < 2; ++it)
            op[it * 2 * F_] = acc[it][r];
    }
}

extern "C" void kernel_launch(void* const* d_in, const int* in_sizes, int n_in,
                              void* d_out, int out_size, void* d_ws, size_t ws_size,
                              hipStream_t stream) {
    const float* x    = (const float*)d_in[0];
    const float* kern = (const float*)d_in[1];
    const float* tker = (const float*)d_in[2];
    float* out = (float*)d_out;

    hipLaunchKernelGGL(mtp_prep, dim3(9), dim3(256), 0, stream, kern, tker);
    hipLaunchKernelGGL(mtp_main, dim3(B_ * H_ * 4), dim3(256), 0, stream, x, out);
}

// Round 20
// 16.883 us; speedup vs baseline: 1.2975x; 1.2975x over previous
//
#include <hip/hip_runtime.h>

// Problem constants (from reference setup_inputs)
#define B_  4
#define H_  64
#define W_  64
#define C_  16
#define F_  32

#define NWE (8 * 9 * F_)   // 2304 weight entries; each = 2 h2 (wt, wk) = 8 B
#define NXE (3 * 34 * 4)   // 408 x-stage chunks (4 channels each)

typedef _Float16 h2 __attribute__((ext_vector_type(2)));

__device__ __forceinline__ h2 pack2(float a, float b) {
    h2 r; r.x = (_Float16)a; r.y = (_Float16)b; return r;
}

// acc += m.x + m.y (f32 accumulate of a packed f16 pair)
__device__ __forceinline__ float acc_dot2(h2 m, float c) {
#if __has_builtin(__builtin_amdgcn_fdot2)
    h2 one; one.x = (_Float16)1.0f; one.y = (_Float16)1.0f;
    return __builtin_amdgcn_fdot2(m, one, c, false);
#else
    return c + (float)m.x + (float)m.y;
#endif
}

// Round-20 = round-13 champion (16.95us) with ONE change: cc-loop unroll 2.
// Rationale: real grid = 512 blocks -> 2 waves/SIMD; TLP can't hide the
// per-cc {36 DS loads -> compute} dependency. unroll 2 gives ILP instead:
// batch k+1's loads issue under batch k's ~300cyc compute. Live regs ~116
// < 128 with no launch_bounds floor -> no spill expected (r14's unroll-2
// test was confounded by a layout change; this is the clean A/B).
// Fallback: if this regresses, r13 verbatim is the declared final.
__global__ __launch_bounds__(256) void mtp_main(const float* __restrict__ x,
                                                const float* __restrict__ kern,
                                                const float* __restrict__ tker,
                                                float* __restrict__ out) {
    __shared__ h2 wlds[NWE * 2];        // [ccp(8)][q(9)][f(32)][{wt,wk}]  18432 B
    __shared__ h2 xlds[3][34][8];       // [row][padded col][ch pair]       3264 B

    const int tid  = threadIdx.x;
    const int bidx = blockIdx.x;        // (b*64 + i)*2 + half
    const int half = bidx & 1;
    const int i    = (bidx >> 1) & 63;
    const int b    = bidx >> 7;

    // ---- stage weights (f32 -> packed f16): consecutive tid = consecutive f
    #pragma unroll
    for (int e0 = 0; e0 < 9; ++e0) {
        int e   = e0 * 256 + tid;       // 2304 = 9*256 exactly
        int f   = e & 31;
        int t   = e >> 5;
        int q   = t % 9;
        int ccp = t / 9;
        int s0 = (q * C_ + ccp * 2 + 0) * F_ + f;
        int s1 = (q * C_ + ccp * 2 + 1) * F_ + f;
        wlds[e * 2 + 0] = pack2(tker[s0], tker[s1]);   // wt = times (slope)
        wlds[e * 2 + 1] = pack2(kern[s0], kern[s1]);   // wk = plus (offset)
    }
    // ---- stage x halo (zero-padded, f32 -> packed f16) ----
    for (int e = tid; e < NXE; e += 256) {
        int cc4 = e & 3;
        int t   = e >> 2;
        int cl  = t % 34;               // local padded col
        int di  = t / 34;
        int ro  = i + di - 1;
        int co  = half * 32 + cl - 1;
        float4 v = make_float4(0.f, 0.f, 0.f, 0.f);
        if (ro >= 0 && ro < H_ && co >= 0 && co < W_)
            v = *reinterpret_cast<const float4*>(
                    x + ((b * H_ + ro) * W_ + co) * C_ + cc4 * 4);
        xlds[di][cl][cc4 * 2 + 0] = pack2(v.x, v.y);
        xlds[di][cl][cc4 * 2 + 1] = pack2(v.z, v.w);
    }
    __syncthreads();

    const int lane = tid & 63;
    const int f    = lane & 31;
    const int ps   = lane >> 5;
    const int w    = tid >> 6;          // wave 0..3
    const int cb   = w * 8 + ps;        // padded-col base for lc=0

    float acc[4][4];                    // [it][r]
    #pragma unroll
    for (int it = 0; it < 4; ++it)
        #pragma unroll
        for (int r = 0; r < 4; ++r) acc[it][r] = 0.f;

    #pragma unroll 2
    for (int cc = 0; cc < 8; ++cc) {
        // weights: 9 x 8B (wt,wk adjacent -> merged ds_read)
        h2 wt[9], wk[9];
        #pragma unroll
        for (int q = 0; q < 9; ++q) {
            int bi = ((cc * 9 + q) * F_ + f) * 2;
            wt[q] = wlds[bi];
            wk[q] = wlds[bi + 1];
        }
        // x halo: 3 rows x 9 cols, 4B each (2 distinct addrs/wave -> broadcast)
        h2 xh[3][9];
        #pragma unroll
        for (int dr = 0; dr < 3; ++dr)
            #pragma unroll
            for (int lc = 0; lc < 9; ++lc)
                xh[dr][lc] = xlds[dr][cb + lc][cc];

        #pragma unroll
        for (int it = 0; it < 4; ++it) {
            #pragma unroll
            for (int r = 0; r < 4; ++r) {
                h2 z[9];
                #pragma unroll
                for (int q = 0; q < 9; ++q) {
                    const int a = q / 3, bq = q % 3;
                    int di, dj;
                    switch (r) {   // x position = rot_r^{-1}(weight position q)
                        case 0:  di = a;      dj = bq;     break;
                        case 1:  di = 2 - bq; dj = a;      break;
                        case 2:  di = 2 - a;  dj = 2 - bq; break;
                        default: di = bq;     dj = 2 - a;  break;
                    }
                    // v_pk_fma_f16 via fp-contract on packed mul+add
                    z[q] = xh[di][it * 2 + dj] * wt[q] + wk[q];
                }
                h2 m1 = __builtin_elementwise_max(__builtin_elementwise_max(z[0], z[1]), z[2]);
                h2 m2 = __builtin_elementwise_max(__builtin_elementwise_max(z[3], z[4]), z[5]);
                h2 m3 = __builtin_elementwise_max(__builtin_elementwise_max(z[6], z[7]), z[8]);
                h2 mm = __builtin_elementwise_max(__builtin_elementwise_max(m1, m2), m3);
                acc[it][r] = acc_dot2(mm, acc[it][r]);   // f32 accumulate
            }
        }
    }

    // ---- store: out[b, r, i, jg + it*2, f]
    const int jg = half * 32 + w * 8 + ps;
    #pragma unroll
    for (int r = 0; r < 4; ++r) {
        float* op = out + ((((b * 4 + r) * H_ + i) * W_ + jg) * F_ + f);
        #pragma unroll
        for (int it = 0; it < 4; ++it)
            op[it * 2 * F_] = acc[it][r];
    }
}

extern "C" void kernel_launch(void* const* d_in, const int* in_sizes, int n_in,
                              void* d_out, int out_size, void* d_ws, size_t ws_size,
                              hipStream_t stream) {
    const float* x    = (const float*)d_in[0];
    const float* kern = (const float*)d_in[1];
    const float* tker = (const float*)d_in[2];
    float* out = (float*)d_out;

    hipLaunchKernelGGL(mtp_main, dim3(B_ * H_ * 2), dim3(256), 0, stream,
                       x, kern, tker, out);
}

// Round 21
// 16.461 us; speedup vs baseline: 1.3308x; 1.0257x over previous
//
#include <hip/hip_runtime.h>

// Problem constants (from reference setup_inputs)
#define B_  4
#define H_  64
#define W_  64
#define C_  16
#define F_  32

#define NWE (8 * 9 * F_)   // 2304 weight entries; each = 2 h2 (wt, wk) = 8 B
#define NXE (3 * 66 * 4)   // 792 x-stage float4 chunks (full-row halo)

typedef _Float16 h2 __attribute__((ext_vector_type(2)));

__device__ __forceinline__ h2 pack2(float a, float b) {
    h2 r; r.x = (_Float16)a; r.y = (_Float16)b; return r;
}

// acc += m.x + m.y (f32 accumulate of a packed f16 pair)
__device__ __forceinline__ float acc_dot2(h2 m, float c) {
#if __has_builtin(__builtin_amdgcn_fdot2)
    h2 one; one.x = (_Float16)1.0f; one.y = (_Float16)1.0f;
    return __builtin_amdgcn_fdot2(m, one, c, false);
#else
    return c + (float)m.x + (float)m.y;
#endif
}

// Round-21 = r13/r20 math CONSOLIDATED: one 1024-thr block per (b,i) row,
// grid 256 (1 block/CU). Motivation (r17 + r16/r18/r19 synthesis):
//  - weight staging paid ONCE per CU (was twice by 2 co-resident 256-thr
//    blocks) and spread over 4x threads -> staging phase ~4x shorter;
//  - compute residency doubles: 16 waves/CU = 4 waves/SIMD (r17's regime).
// Wave = 4-px strip (it=2); per-px DS rises slightly but DS count is proven
// non-binding (r10/r12/r15). LDS 24.8 KB; est VGPR ~64; no launch_bounds
// floor (r4/r8/r11); cc-loop unroll 2 (r20, neutral-to-slightly-better).
__global__ __launch_bounds__(1024) void mtp_main(const float* __restrict__ x,
                                                 const float* __restrict__ kern,
                                                 const float* __restrict__ tker,
                                                 float* __restrict__ out) {
    __shared__ h2 wlds[NWE * 2];        // [ccp(8)][q(9)][f(32)][{wt,wk}]  18432 B
    __shared__ h2 xlds[3][66][8];       // [row][padded col][ch pair]       6336 B

    const int tid  = threadIdx.x;       // 0..1023
    const int bidx = blockIdx.x;        // b*64 + i
    const int i    = bidx & 63;
    const int b    = bidx >> 6;

    // ---- stage weights (f32 -> packed f16): 2304 entries over 1024 threads
    for (int e = tid; e < NWE; e += 1024) {
        int f   = e & 31;
        int t   = e >> 5;
        int q   = t % 9;
        int ccp = t / 9;
        int s0 = (q * C_ + ccp * 2 + 0) * F_ + f;
        int s1 = (q * C_ + ccp * 2 + 1) * F_ + f;
        wlds[e * 2 + 0] = pack2(tker[s0], tker[s1]);   // wt = times (slope)
        wlds[e * 2 + 1] = pack2(kern[s0], kern[s1]);   // wk = plus (offset)
    }
    // ---- stage x halo (zero-padded): rows i-1..i+1, full row, padded cols 0..65
    for (int e = tid; e < NXE; e += 1024) {
        int cc4 = e & 3;
        int t   = e >> 2;
        int cl  = t % 66;               // local padded col
        int di  = t / 66;
        int ro  = i + di - 1;
        int co  = cl - 1;
        float4 v = make_float4(0.f, 0.f, 0.f, 0.f);
        if (ro >= 0 && ro < H_ && co >= 0 && co < W_)
            v = *reinterpret_cast<const float4*>(
                    x + ((b * H_ + ro) * W_ + co) * C_ + cc4 * 4);
        xlds[di][cl][cc4 * 2 + 0] = pack2(v.x, v.y);
        xlds[di][cl][cc4 * 2 + 1] = pack2(v.z, v.w);
    }
    __syncthreads();

    const int lane = tid & 63;
    const int f    = lane & 31;
    const int ps   = lane >> 5;
    const int w    = tid >> 6;          // wave 0..15; strip = px w*4 .. w*4+3
    const int cb   = w * 4 + ps;        // padded-col base for lc=0

    float acc[2][4];                    // [it][r]
    #pragma unroll
    for (int it = 0; it < 2; ++it)
        #pragma unroll
        for (int r = 0; r < 4; ++r) acc[it][r] = 0.f;

    #pragma unroll 2
    for (int cc = 0; cc < 8; ++cc) {
        // weights: 9 x 8B (wt,wk adjacent -> merged ds_read)
        h2 wt[9], wk[9];
        #pragma unroll
        for (int q = 0; q < 9; ++q) {
            int bi = ((cc * 9 + q) * F_ + f) * 2;
            wt[q] = wlds[bi];
            wk[q] = wlds[bi + 1];
        }
        // x halo: 3 rows x 5 cols, 4B each (2 distinct addrs/wave -> broadcast)
        h2 xh[3][5];
        #pragma unroll
        for (int dr = 0; dr < 3; ++dr)
            #pragma unroll
            for (int lc = 0; lc < 5; ++lc)
                xh[dr][lc] = xlds[dr][cb + lc][cc];

        #pragma unroll
        for (int it = 0; it < 2; ++it) {
            #pragma unroll
            for (int r = 0; r < 4; ++r) {
                h2 z[9];
                #pragma unroll
                for (int q = 0; q < 9; ++q) {
                    const int a = q / 3, bq = q % 3;
                    int di, dj;
                    switch (r) {   // x position = rot_r^{-1}(weight position q)
                        case 0:  di = a;      dj = bq;     break;
                        case 1:  di = 2 - bq; dj = a;      break;
                        case 2:  di = 2 - a;  dj = 2 - bq; break;
                        default: di = bq;     dj = 2 - a;  break;
                    }
                    // v_pk_fma_f16 via fp-contract on packed mul+add
                    z[q] = xh[di][it * 2 + dj] * wt[q] + wk[q];
                }
                h2 m1 = __builtin_elementwise_max(__builtin_elementwise_max(z[0], z[1]), z[2]);
                h2 m2 = __builtin_elementwise_max(__builtin_elementwise_max(z[3], z[4]), z[5]);
                h2 m3 = __builtin_elementwise_max(__builtin_elementwise_max(z[6], z[7]), z[8]);
                h2 mm = __builtin_elementwise_max(__builtin_elementwise_max(m1, m2), m3);
                acc[it][r] = acc_dot2(mm, acc[it][r]);   // f32 accumulate
            }
        }
    }

    // ---- store: out[b, r, i, jg + it*2, f]; per (r,it) wave stores 256B
    const int jg = w * 4 + ps;
    #pragma unroll
    for (int r = 0; r < 4; ++r) {
        float* op = out + ((((b * 4 + r) * H_ + i) * W_ + jg) * F_ + f);
        #pragma unroll
        for (int it = 0; it < 2; ++it)
            op[it * 2 * F_] = acc[it][r];
    }
}

extern "C" void kernel_launch(void* const* d_in, const int* in_sizes, int n_in,
                              void* d_out, int out_size, void* d_ws, size_t ws_size,
                              hipStream_t stream) {
    const float* x    = (const float*)d_in[0];
    const float* kern = (const float*)d_in[1];
    const float* tker = (const float*)d_in[2];
    float* out = (float*)d_out;

    hipLaunchKernelGGL(mtp_main, dim3(B_ * H_), dim3(1024), 0, stream,
                       x, kern, tker, out);
}